// Round 6
// baseline (495.710 us; speedup 1.0000x reference)
//
#include <hip/hip_runtime.h>

#define HIDDEN 128
#define SCAN_CHUNK 256

// ---------------------------------------------------------------------------
// CSR build step 1: degree histogram over dst
// ---------------------------------------------------------------------------
__global__ __launch_bounds__(256) void hist_kernel(const int* __restrict__ dst,
                                                   int* __restrict__ deg, int E) {
  int e = blockIdx.x * blockDim.x + threadIdx.x;
  if (e < E) atomicAdd(&deg[dst[e]], 1);
}

// ---------------------------------------------------------------------------
// CSR scan phase A: per-block chunk sums (chunk = 256 elements, 1/thread)
// ---------------------------------------------------------------------------
__global__ __launch_bounds__(256) void scan_partial_kernel(
    const int* __restrict__ deg, int* __restrict__ partial, int N) {
  __shared__ int red[256];
  const int t = threadIdx.x;
  const int idx = blockIdx.x * SCAN_CHUNK + t;
  red[t] = (idx < N) ? deg[idx] : 0;
  __syncthreads();
#pragma unroll
  for (int off = 128; off; off >>= 1) {
    if (t < off) red[t] += red[t + off];
    __syncthreads();
  }
  if (t == 0) partial[blockIdx.x] = red[0];
}

// ---------------------------------------------------------------------------
// CSR scan phase B: one block scans the (<=256) block partials -> exclusive
// block offsets.
// ---------------------------------------------------------------------------
__global__ __launch_bounds__(256) void scan_offsets_kernel(
    const int* __restrict__ partial, int* __restrict__ blockOff, int nBlocks) {
  __shared__ int sums[256];
  const int t = threadIdx.x;
  const int p = (t < nBlocks) ? partial[t] : 0;
  sums[t] = p;
  __syncthreads();
#pragma unroll
  for (int off = 1; off < 256; off <<= 1) {
    int v = (t >= off) ? sums[t - off] : 0;
    __syncthreads();
    sums[t] += v;
    __syncthreads();
  }
  blockOff[t] = sums[t] - p;  // exclusive
}

// ---------------------------------------------------------------------------
// CSR scan phase C: per-block exclusive scan of its chunk + block offset;
// writes rowptr AND cursor.
// ---------------------------------------------------------------------------
__global__ __launch_bounds__(256) void scan_final_kernel(
    const int* __restrict__ deg, const int* __restrict__ blockOff,
    int* __restrict__ rowptr, int* __restrict__ cursor, int N) {
  __shared__ int sh[256];
  const int t = threadIdx.x;
  const int idx = blockIdx.x * SCAN_CHUNK + t;
  const int v = (idx < N) ? deg[idx] : 0;
  sh[t] = v;
  __syncthreads();
#pragma unroll
  for (int off = 1; off < 256; off <<= 1) {
    int u = (t >= off) ? sh[t - off] : 0;
    __syncthreads();
    sh[t] += u;
    __syncthreads();
  }
  const int excl = sh[t] - v + blockOff[blockIdx.x];
  if (idx < N) {
    rowptr[idx] = excl;
    cursor[idx] = excl;
    if (idx == N - 1) rowptr[N] = excl + v;
  }
}

// ---------------------------------------------------------------------------
// CSR build step 3: fill column (src) lists using per-node cursors
// ---------------------------------------------------------------------------
__global__ __launch_bounds__(256) void fill_kernel(const int* __restrict__ src,
                                                   const int* __restrict__ dst,
                                                   int* __restrict__ cursor,
                                                   int* __restrict__ col, int E) {
  int e = blockIdx.x * blockDim.x + threadIdx.x;
  if (e >= E) return;
  int pos = atomicAdd(&cursor[dst[e]], 1);
  col[pos] = src[e];
}

// ---------------------------------------------------------------------------
// One GEMM pass over K=128 for a 32-row LDS tile.
// Thread map: tx = t&15 owns cols tx*8..tx*8+7, ty = t>>4 owns rows ty*2+i.
// Weights straight from global (L1/L2-resident, coalesced 512 B rows);
// 1-step register prefetch on BOTH xs rows and weights; (k+4)&127 wrap keeps
// the prefetch in-bounds on the last iter.
// ---------------------------------------------------------------------------
__device__ __forceinline__ void gemm_pass(const float (*xs)[132],
                                          const float* __restrict__ Wp,
                                          int ty, float acc[2][8]) {
  float4 a[2], w[4][2];
  a[0] = *(const float4*)&xs[ty * 2 + 0][0];
  a[1] = *(const float4*)&xs[ty * 2 + 1][0];
#pragma unroll
  for (int kk = 0; kk < 4; ++kk) {
    w[kk][0] = *(const float4*)(Wp + (size_t)kk * HIDDEN);
    w[kk][1] = *(const float4*)(Wp + (size_t)kk * HIDDEN + 4);
  }
#pragma unroll 1
  for (int k = 0; k < HIDDEN; k += 4) {
    const int kn = (k + 4) & (HIDDEN - 1);
    float4 an[2], wn[4][2];
    an[0] = *(const float4*)&xs[ty * 2 + 0][kn];
    an[1] = *(const float4*)&xs[ty * 2 + 1][kn];
#pragma unroll
    for (int kk = 0; kk < 4; ++kk) {
      wn[kk][0] = *(const float4*)(Wp + (size_t)(kn + kk) * HIDDEN);
      wn[kk][1] = *(const float4*)(Wp + (size_t)(kn + kk) * HIDDEN + 4);
    }
#pragma unroll
    for (int i = 0; i < 2; ++i) {
      const float ak0 = a[i].x, ak1 = a[i].y, ak2 = a[i].z, ak3 = a[i].w;
      acc[i][0] += ak0 * w[0][0].x + ak1 * w[1][0].x + ak2 * w[2][0].x + ak3 * w[3][0].x;
      acc[i][1] += ak0 * w[0][0].y + ak1 * w[1][0].y + ak2 * w[2][0].y + ak3 * w[3][0].y;
      acc[i][2] += ak0 * w[0][0].z + ak1 * w[1][0].z + ak2 * w[2][0].z + ak3 * w[3][0].z;
      acc[i][3] += ak0 * w[0][0].w + ak1 * w[1][0].w + ak2 * w[2][0].w + ak3 * w[3][0].w;
      acc[i][4] += ak0 * w[0][1].x + ak1 * w[1][1].x + ak2 * w[2][1].x + ak3 * w[3][1].x;
      acc[i][5] += ak0 * w[0][1].y + ak1 * w[1][1].y + ak2 * w[2][1].y + ak3 * w[3][1].y;
      acc[i][6] += ak0 * w[0][1].z + ak1 * w[1][1].z + ak2 * w[2][1].z + ak3 * w[3][1].z;
      acc[i][7] += ak0 * w[0][1].w + ak1 * w[1][1].w + ak2 * w[2][1].w + ak3 * w[3][1].w;
    }
#pragma unroll
    for (int i = 0; i < 2; ++i) a[i] = an[i];
#pragma unroll
    for (int kk = 0; kk < 4; ++kk) {
      w[kk][0] = wn[kk][0];
      w[kk][1] = wn[kk][1];
    }
  }
}

// ---------------------------------------------------------------------------
// Fused GIN layer: per 32-node block
//   phase 1 (gather): xs[r,:] = H[node,:] + sum_{j in N(node)} H[j,:]
//   phase 2 (MLP):    h2 = relu( relu(xs@W1+b1) @ W2 + b2 )
//   epilogue:         doReadout ? out[m]=h2[m,:]·Wr+br : Hout[m,:]=h2[m,:]
// Gather stalls (Infinity-Cache supply) overlap other blocks' MLP VALU.
// LDS 16.9 KB; ~120 VGPR -> ~16 waves/CU resident at 6.1 blocks/CU.
// ---------------------------------------------------------------------------
__global__ __launch_bounds__(256) void gin_layer_kernel(
    const float* __restrict__ H, const int* __restrict__ rowptr,
    const int* __restrict__ col, const float* __restrict__ W1,
    const float* __restrict__ b1, const float* __restrict__ W2,
    const float* __restrict__ b2, float* __restrict__ Hout,
    const float* __restrict__ Wr, const float* __restrict__ br,
    float* __restrict__ outv, int M, int doReadout) {
  __shared__ float xs[32][132];
  const int t = threadIdx.x;
  const int mBase = blockIdx.x * 32;

  // ---- phase 1: gather. 4 waves x 8 nodes, lane owns a float2 col slice.
  {
    const int w = t >> 6;
    const int lane = t & 63;
    const int coff = lane * 2;
#pragma unroll 1
    for (int j = 0; j < 8; ++j) {
      const int r = w * 8 + j;
      const int node = mBase + r;
      float2 acc = make_float2(0.f, 0.f);
      if (node < M) {
        acc = *(const float2*)(H + (size_t)node * HIDDEN + coff);
        const int s = rowptr[node];
        const int e = rowptr[node + 1];
        int i = s;
        for (; i + 3 < e; i += 4) {
          int c0 = col[i], c1 = col[i + 1], c2 = col[i + 2], c3 = col[i + 3];
          float2 v0 = *(const float2*)(H + (size_t)c0 * HIDDEN + coff);
          float2 v1 = *(const float2*)(H + (size_t)c1 * HIDDEN + coff);
          float2 v2 = *(const float2*)(H + (size_t)c2 * HIDDEN + coff);
          float2 v3 = *(const float2*)(H + (size_t)c3 * HIDDEN + coff);
          acc.x += v0.x + v1.x + v2.x + v3.x;
          acc.y += v0.y + v1.y + v2.y + v3.y;
        }
        for (; i < e; ++i) {
          int c = col[i];
          float2 v = *(const float2*)(H + (size_t)c * HIDDEN + coff);
          acc.x += v.x;
          acc.y += v.y;
        }
      }
      *(float2*)&xs[r][coff] = acc;
    }
  }
  __syncthreads();

  // ---- phase 2: MLP. tx owns 8 cols, ty owns 2 rows.
  const int tx = t & 15;
  const int ty = t >> 4;

  float acc[2][8];
#pragma unroll
  for (int i = 0; i < 2; ++i)
#pragma unroll
    for (int j = 0; j < 8; ++j) acc[i][j] = 0.f;

  gemm_pass(xs, W1 + tx * 8, ty, acc);

  __syncthreads();  // xs reads done before h1 overwrite
  float4 b1a = *(const float4*)(b1 + tx * 8);
  float4 b1b = *(const float4*)(b1 + tx * 8 + 4);
#pragma unroll
  for (int i = 0; i < 2; ++i) {
    float4 h0, h1;
    h0.x = fmaxf(acc[i][0] + b1a.x, 0.f);
    h0.y = fmaxf(acc[i][1] + b1a.y, 0.f);
    h0.z = fmaxf(acc[i][2] + b1a.z, 0.f);
    h0.w = fmaxf(acc[i][3] + b1a.w, 0.f);
    h1.x = fmaxf(acc[i][4] + b1b.x, 0.f);
    h1.y = fmaxf(acc[i][5] + b1b.y, 0.f);
    h1.z = fmaxf(acc[i][6] + b1b.z, 0.f);
    h1.w = fmaxf(acc[i][7] + b1b.w, 0.f);
    *(float4*)&xs[ty * 2 + i][tx * 8] = h0;
    *(float4*)&xs[ty * 2 + i][tx * 8 + 4] = h1;
#pragma unroll
    for (int j = 0; j < 8; ++j) acc[i][j] = 0.f;
  }
  __syncthreads();

  gemm_pass(xs, W2 + tx * 8, ty, acc);

  float4 b2a = *(const float4*)(b2 + tx * 8);
  float4 b2b = *(const float4*)(b2 + tx * 8 + 4);
  if (!doReadout) {
#pragma unroll
    for (int i = 0; i < 2; ++i) {
      int gm = mBase + ty * 2 + i;
      if (gm >= M) continue;
      float4 o0, o1;
      o0.x = fmaxf(acc[i][0] + b2a.x, 0.f);
      o0.y = fmaxf(acc[i][1] + b2a.y, 0.f);
      o0.z = fmaxf(acc[i][2] + b2a.z, 0.f);
      o0.w = fmaxf(acc[i][3] + b2a.w, 0.f);
      o1.x = fmaxf(acc[i][4] + b2b.x, 0.f);
      o1.y = fmaxf(acc[i][5] + b2b.y, 0.f);
      o1.z = fmaxf(acc[i][6] + b2b.z, 0.f);
      o1.w = fmaxf(acc[i][7] + b2b.w, 0.f);
      *(float4*)(Hout + (size_t)gm * HIDDEN + tx * 8) = o0;
      *(float4*)(Hout + (size_t)gm * HIDDEN + tx * 8 + 4) = o1;
    }
  } else {
    float4 wra = *(const float4*)(Wr + tx * 8);
    float4 wrb = *(const float4*)(Wr + tx * 8 + 4);
    float brv = br[0];
#pragma unroll
    for (int i = 0; i < 2; ++i) {
      float h0 = fmaxf(acc[i][0] + b2a.x, 0.f);
      float h1 = fmaxf(acc[i][1] + b2a.y, 0.f);
      float h2 = fmaxf(acc[i][2] + b2a.z, 0.f);
      float h3 = fmaxf(acc[i][3] + b2a.w, 0.f);
      float h4 = fmaxf(acc[i][4] + b2b.x, 0.f);
      float h5 = fmaxf(acc[i][5] + b2b.y, 0.f);
      float h6 = fmaxf(acc[i][6] + b2b.z, 0.f);
      float h7 = fmaxf(acc[i][7] + b2b.w, 0.f);
      float p = h0 * wra.x + h1 * wra.y + h2 * wra.z + h3 * wra.w +
                h4 * wrb.x + h5 * wrb.y + h6 * wrb.z + h7 * wrb.w;
      // reduce across the 16 tx lanes (xor<16 stays within the tx group)
      p += __shfl_xor(p, 8);
      p += __shfl_xor(p, 4);
      p += __shfl_xor(p, 2);
      p += __shfl_xor(p, 1);
      int gm = mBase + ty * 2 + i;
      if (tx == 0 && gm < M) outv[gm] = p + brv;
    }
  }
}

extern "C" void kernel_launch(void* const* d_in, const int* in_sizes, int n_in,
                              void* d_out, int out_size, void* d_ws,
                              size_t ws_size, hipStream_t stream) {
  const float* x = (const float*)d_in[0];
  const int* ei = (const int*)d_in[1];
  const float* W1_0 = (const float*)d_in[2];
  const float* b1_0 = (const float*)d_in[3];
  const float* W2_0 = (const float*)d_in[4];
  const float* b2_0 = (const float*)d_in[5];
  const float* W1_1 = (const float*)d_in[6];
  const float* b1_1 = (const float*)d_in[7];
  const float* W2_1 = (const float*)d_in[8];
  const float* b2_1 = (const float*)d_in[9];
  const float* Wr = (const float*)d_in[10];
  const float* br = (const float*)d_in[11];

  const int M = in_sizes[0] / HIDDEN;  // 50000 nodes
  const int E = in_sizes[1] / 2;       // 800000 edges
  const int* src = ei;
  const int* dst = ei + E;

  // workspace layout
  float* B = (float*)d_ws;                   // [M,128] layer-0 output
  int* deg = (int*)(B + (size_t)M * HIDDEN); // [M]
  int* rowptr = deg + M;                     // [M+1]
  int* cursor = rowptr + M + 1;              // [M]
  int* col = cursor + M;                     // [E]
  int* partial = col + E;                    // [256]
  int* blockOff = partial + 256;             // [256]

  const int scanBlocks = (M + SCAN_CHUNK - 1) / SCAN_CHUNK;
  const int layerBlocks = (M + 31) / 32;
  float* out = (float*)d_out;

  // ---- build CSR (dst -> list of src), reused by both layers
  hipMemsetAsync(deg, 0, (size_t)M * sizeof(int), stream);
  hist_kernel<<<(E + 255) / 256, 256, 0, stream>>>(dst, deg, E);
  scan_partial_kernel<<<scanBlocks, 256, 0, stream>>>(deg, partial, M);
  scan_offsets_kernel<<<1, 256, 0, stream>>>(partial, blockOff, scanBlocks);
  scan_final_kernel<<<scanBlocks, 256, 0, stream>>>(deg, blockOff, rowptr,
                                                    cursor, M);
  fill_kernel<<<(E + 255) / 256, 256, 0, stream>>>(src, dst, cursor, col, E);

  // ---- layer 0: fused gather+MLP -> B
  gin_layer_kernel<<<layerBlocks, 256, 0, stream>>>(
      x, rowptr, col, W1_0, b1_0, W2_0, b2_0, B, nullptr, nullptr, nullptr, M, 0);

  // ---- layer 1: fused gather+MLP+readout -> out
  gin_layer_kernel<<<layerBlocks, 256, 0, stream>>>(
      B, rowptr, col, W1_1, b1_1, W2_1, b2_1, nullptr, Wr, br, out, M, 1);
}